// Round 1
// baseline (910.955 us; speedup 1.0000x reference)
//
#include <hip/hip_runtime.h>
#include <hip/hip_fp16.h>

typedef unsigned short u16;
typedef __attribute__((ext_vector_type(8))) _Float16 f16x8;
typedef __attribute__((ext_vector_type(4))) float f32x4;

static __device__ __forceinline__ u16 f2h(float f) {
    __half h = __float2half(f);
    return __half_as_ushort(h);
}

// ---------------- RoPE tables: cos/sin[s][i], s<2048, i<64 ----------------
__global__ __launch_bounds__(256) void k_rope_tables(float* __restrict__ ct, float* __restrict__ st) {
    int idx = blockIdx.x * 256 + threadIdx.x;   // 2048*64 total
    int s = idx >> 6, i = idx & 63;
    float inv = 1.0f / powf(10000.0f, (float)i * (1.0f / 64.0f));
    float f = (float)s * inv;
    ct[idx] = cosf(f);
    st[idx] = sinf(f);
}

// ---------------- per-row absmax int8 quant (stored as exact-int f16) ----------------
// src: [rows][2048] f32 ; dst: [rows][2048] f16 ; scales[row]
__global__ __launch_bounds__(256) void k_quant_rows(const float* __restrict__ src,
        u16* __restrict__ dst, float* __restrict__ scales) {
    int row = blockIdx.x;
    const float* p = src + (size_t)row * 2048;
    int t = threadIdx.x;
    float4 v0 = ((const float4*)p)[t * 2 + 0];
    float4 v1 = ((const float4*)p)[t * 2 + 1];
    float amax = fmaxf(
        fmaxf(fmaxf(fabsf(v0.x), fabsf(v0.y)), fmaxf(fabsf(v0.z), fabsf(v0.w))),
        fmaxf(fmaxf(fabsf(v1.x), fabsf(v1.y)), fmaxf(fabsf(v1.z), fabsf(v1.w))));
#pragma unroll
    for (int d = 1; d < 64; d <<= 1) amax = fmaxf(amax, __shfl_xor(amax, d, 64));
    __shared__ float red[4];
    if ((t & 63) == 0) red[t >> 6] = amax;
    __syncthreads();
    amax = fmaxf(fmaxf(red[0], red[1]), fmaxf(red[2], red[3]));
    float scl = fmaxf(amax * (1.0f / 127.0f), 1e-5f);
    if (t == 0) scales[row] = scl;
    float vv[8] = {v0.x, v0.y, v0.z, v0.w, v1.x, v1.y, v1.z, v1.w};
    u16 q[8];
#pragma unroll
    for (int j = 0; j < 8; ++j) {
        float r = rintf(vv[j] / scl);           // RNE, matches jnp.round
        r = fminf(fmaxf(r, -127.0f), 127.0f);
        q[j] = f2h(r);                          // exact: |int| <= 127
    }
    *(uint4*)&dst[(size_t)row * 2048 + t * 8] = *(uint4*)q;
}

// ---------------- quantized GEMM: out[m][n] = (A[m,:].B[n,:]) * as[m]*ws[n] ----------------
#define BM 128
#define BN 128
#define BK 64
#define LDSP 72   // BK + 8 pad elements -> 144B row stride (bank-friendly, 16B aligned)

__global__ __launch_bounds__(256) void k_gemm_q(const u16* __restrict__ A,
        const u16* __restrict__ B, const float* __restrict__ ascale,
        const float* __restrict__ wscale, float* __restrict__ out,
        int M, int N, int K) {
    __shared__ u16 As[BM][LDSP];
    __shared__ u16 Bs[BN][LDSP];
    int t = threadIdx.x;
    int wid = t >> 6, lane = t & 63;
    int bm = blockIdx.y * BM, bn = blockIdx.x * BN;
    int wm = (wid >> 1) * 64, wn = (wid & 1) * 64;
    int rl = lane & 15, kg = lane >> 4;

    f32x4 z = {0.f, 0.f, 0.f, 0.f};
    f32x4 acc[4][4];
#pragma unroll
    for (int i = 0; i < 4; ++i)
#pragma unroll
        for (int j = 0; j < 4; ++j) acc[i][j] = z;

    int sr = t >> 3, sc = (t & 7) * 8;
    const u16* Ab = A + (size_t)(bm + sr) * K + sc;
    const u16* Bb = B + (size_t)(bn + sr) * K + sc;
    uint4 ra[4], rb[4];
#pragma unroll
    for (int p = 0; p < 4; ++p) {
        ra[p] = *(const uint4*)(Ab + (size_t)p * 32 * K);
        rb[p] = *(const uint4*)(Bb + (size_t)p * 32 * K);
    }
    int NT = K / BK;
    for (int kt = 0; kt < NT; ++kt) {
#pragma unroll
        for (int p = 0; p < 4; ++p) {
            *(uint4*)&As[sr + p * 32][sc] = ra[p];
            *(uint4*)&Bs[sr + p * 32][sc] = rb[p];
        }
        __syncthreads();
        if (kt + 1 < NT) {
            size_t koff = (size_t)(kt + 1) * BK;
#pragma unroll
            for (int p = 0; p < 4; ++p) {
                ra[p] = *(const uint4*)(Ab + (size_t)p * 32 * K + koff);
                rb[p] = *(const uint4*)(Bb + (size_t)p * 32 * K + koff);
            }
        }
#pragma unroll
        for (int ks = 0; ks < 2; ++ks) {
            f16x8 af[4], bfr[4];
#pragma unroll
            for (int i = 0; i < 4; ++i)
                af[i] = *(const f16x8*)&As[wm + i * 16 + rl][ks * 32 + kg * 8];
#pragma unroll
            for (int j = 0; j < 4; ++j)
                bfr[j] = *(const f16x8*)&Bs[wn + j * 16 + rl][ks * 32 + kg * 8];
#pragma unroll
            for (int i = 0; i < 4; ++i)
#pragma unroll
                for (int j = 0; j < 4; ++j)
                    acc[i][j] = __builtin_amdgcn_mfma_f32_16x16x32_f16(af[i], bfr[j], acc[i][j], 0, 0, 0);
        }
        __syncthreads();
    }
#pragma unroll
    for (int i = 0; i < 4; ++i) {
#pragma unroll
        for (int j = 0; j < 4; ++j) {
            int n = bn + wn + j * 16 + rl;
            float wsn = wscale[n];
#pragma unroll
            for (int r = 0; r < 4; ++r) {
                int m = bm + wm + i * 16 + kg * 4 + r;
                out[(size_t)m * N + n] = acc[i][j][r] * ascale[m] * wsn;
            }
        }
    }
}

// ---------------- fused RMSNorm + RoPE + gain, split to q/k/v f16 buffers ----------------
// qkv: [4096][3072] f32. Per wave: one (token, unit). units 0-15: q heads, 16-19: k heads, 20-23: v chunks.
__global__ __launch_bounds__(256) void k_rmsrope(const float* __restrict__ qkv,
        const float* __restrict__ qgain, const float* __restrict__ ct,
        const float* __restrict__ st, u16* __restrict__ qb,
        u16* __restrict__ kb, u16* __restrict__ vb) {
    int wave = blockIdx.x * 4 + (threadIdx.x >> 6);
    int lane = threadIdx.x & 63;
    int token = wave / 24, unit = wave - token * 24;
    int b = token >> 11, s = token & 2047;
    int col;
    if (unit < 16) col = unit * 128;
    else if (unit < 20) col = 2048 + (unit - 16) * 128;
    else col = 2560 + (unit - 20) * 128;
    const float* p = qkv + (size_t)token * 3072 + col;
    float x1 = p[lane], x2 = p[lane + 64];
    if (unit < 20) {
        float ss = x1 * x1 + x2 * x2;
#pragma unroll
        for (int d = 1; d < 64; d <<= 1) ss += __shfl_xor(ss, d, 64);
        float rn = rsqrtf(ss * (1.0f / 128.0f) + 1.1920929e-07f);
        x1 *= rn; x2 *= rn;
        float c = ct[s * 64 + lane], sn = st[s * 64 + lane];
        float o1 = x1 * c + x2 * sn;
        float o2 = x2 * c - x1 * sn;
        if (unit < 16) {
            float g = qgain[unit] * 0.08838834764831845f;  // fold 1/sqrt(128) into q
            o1 *= g; o2 *= g;
        }
        x1 = o1; x2 = o2;
    }
    u16 u1 = f2h(x1), u2 = f2h(x2);
    size_t off; u16* dst;
    if (unit < 16)      { dst = qb; off = ((size_t)(b * 16 + unit) * 2048 + s) * 128; }
    else if (unit < 20) { dst = kb; off = ((size_t)(b * 4 + (unit - 16)) * 2048 + s) * 128; }
    else                { dst = vb; off = ((size_t)(b * 4 + (unit - 20)) * 2048 + s) * 128; }
    dst[off + lane] = u1;
    dst[off + lane + 64] = u2;
}

// ---------------- V transpose: [bh][s][128] -> [bh][d][2048] ----------------
__global__ __launch_bounds__(256) void k_transpose_v(const u16* __restrict__ vb,
        u16* __restrict__ vt) {
    __shared__ u16 tls[64][72];
    int bh = blockIdx.x;          // 8
    int s0 = blockIdx.y * 64;     // 32
    int d0 = blockIdx.z * 64;     // 2
    const u16* src = vb + (size_t)bh * 2048 * 128;
    u16* dst = vt + (size_t)bh * 128 * 2048;
    int r = threadIdx.x >> 3, c = (threadIdx.x & 7) * 8;
#pragma unroll
    for (int p = 0; p < 2; ++p) {
        uint4 d4 = *(const uint4*)&src[(size_t)(s0 + r + p * 32) * 128 + d0 + c];
        u16 tmp[8]; *(uint4*)tmp = d4;
#pragma unroll
        for (int j = 0; j < 8; ++j) tls[c + j][r + p * 32] = tmp[j];
    }
    __syncthreads();
#pragma unroll
    for (int p = 0; p < 2; ++p) {
        int dd = r + p * 32;
        u16 tmp[8];
#pragma unroll
        for (int j = 0; j < 8; ++j) tmp[j] = tls[dd][c + j];
        *(uint4*)&dst[(size_t)(d0 + dd) * 2048 + s0 + c] = *(uint4*)tmp;
    }
}

// ---------------- flash attention: causal GQA, per-wave 16 q rows ----------------
__global__ __launch_bounds__(256) void k_attn(const u16* __restrict__ qb,
        const u16* __restrict__ kb, const u16* __restrict__ vt,
        float* __restrict__ y) {
    int qc = blockIdx.x, h = blockIdx.y, b = blockIdx.z;
    int wid = threadIdx.x >> 6, lane = threadIdx.x & 63;
    int kvh = h >> 2;
    int q0 = qc * 64 + wid * 16;
    int rl = lane & 15, kg = lane >> 4;
    const u16* qp = qb + ((size_t)(b * 16 + h) * 2048 + q0) * 128;
    const u16* kp = kb + (size_t)(b * 4 + kvh) * 2048 * 128;
    const u16* vp = vt + (size_t)(b * 4 + kvh) * 128 * 2048;
    __shared__ u16 Ps[4][16][40];

    f16x8 qf[4];
#pragma unroll
    for (int kc = 0; kc < 4; ++kc)
        qf[kc] = *(const f16x8*)&qp[(size_t)rl * 128 + kc * 32 + kg * 8];

    f32x4 z = {0.f, 0.f, 0.f, 0.f};
    f32x4 o[8];
#pragma unroll
    for (int j = 0; j < 8; ++j) o[j] = z;
    float mrow[4], lrow[4];
#pragma unroll
    for (int r = 0; r < 4; ++r) { mrow[r] = -3.0e38f; lrow[r] = 0.f; }

    int nsteps = (q0 + 47) >> 5;   // kv tiles of 32 covering cols <= q0+15
    for (int tstep = 0; tstep < nsteps; ++tstep) {
        int kv0 = tstep * 32;
        f32x4 sc[2];
#pragma unroll
        for (int nt = 0; nt < 2; ++nt) {
            f32x4 acc = z;
            const u16* kr = kp + (size_t)(kv0 + nt * 16 + rl) * 128 + kg * 8;
#pragma unroll
            for (int kc = 0; kc < 4; ++kc) {
                f16x8 kf = *(const f16x8*)(kr + kc * 32);
                acc = __builtin_amdgcn_mfma_f32_16x16x32_f16(qf[kc], kf, acc, 0, 0, 0);
            }
            sc[nt] = acc;
        }
        float alpha[4];
#pragma unroll
        for (int r = 0; r < 4; ++r) {
            int grow = q0 + kg * 4 + r;
            float s0v = sc[0][r], s1v = sc[1][r];
            if (kv0 + rl > grow) s0v = -3.0e38f;
            if (kv0 + 16 + rl > grow) s1v = -3.0e38f;
            float mx = fmaxf(s0v, s1v);
            mx = fmaxf(mx, __shfl_xor(mx, 1, 64));
            mx = fmaxf(mx, __shfl_xor(mx, 2, 64));
            mx = fmaxf(mx, __shfl_xor(mx, 4, 64));
            mx = fmaxf(mx, __shfl_xor(mx, 8, 64));
            float mnew = fmaxf(mrow[r], mx);
            float a = __expf(mrow[r] - mnew);
            s0v = __expf(s0v - mnew);
            s1v = __expf(s1v - mnew);
            sc[0][r] = s0v; sc[1][r] = s1v;
            float rs = s0v + s1v;
            rs += __shfl_xor(rs, 1, 64);
            rs += __shfl_xor(rs, 2, 64);
            rs += __shfl_xor(rs, 4, 64);
            rs += __shfl_xor(rs, 8, 64);
            lrow[r] = lrow[r] * a + rs;
            mrow[r] = mnew;
            alpha[r] = a;
        }
#pragma unroll
        for (int j = 0; j < 8; ++j) {
            o[j][0] *= alpha[0];
            o[j][1] *= alpha[1];
            o[j][2] *= alpha[2];
            o[j][3] *= alpha[3];
        }
        // P: C-layout -> A-layout via per-wave LDS bounce
#pragma unroll
        for (int nt = 0; nt < 2; ++nt)
#pragma unroll
            for (int r = 0; r < 4; ++r)
                Ps[wid][kg * 4 + r][nt * 16 + rl] = f2h(sc[nt][r]);
        f16x8 pa = *(const f16x8*)&Ps[wid][rl][kg * 8];
#pragma unroll
        for (int j = 0; j < 8; ++j) {
            f16x8 vf = *(const f16x8*)&vp[(size_t)(j * 16 + rl) * 2048 + kv0 + kg * 8];
            o[j] = __builtin_amdgcn_mfma_f32_16x16x32_f16(pa, vf, o[j], 0, 0, 0);
        }
    }
#pragma unroll
    for (int r = 0; r < 4; ++r) lrow[r] = 1.0f / lrow[r];
#pragma unroll
    for (int j = 0; j < 8; ++j)
#pragma unroll
        for (int r = 0; r < 4; ++r) {
            int grow = q0 + kg * 4 + r;
            y[(size_t)(b * 2048 + grow) * 2048 + h * 128 + j * 16 + rl] = o[j][r] * lrow[r];
        }
}

extern "C" void kernel_launch(void* const* d_in, const int* in_sizes, int n_in,
                              void* d_out, int out_size, void* d_ws, size_t ws_size,
                              hipStream_t stream) {
    const float* x     = (const float*)d_in[0];
    const float* w_q   = (const float*)d_in[1];
    const float* w_k   = (const float*)d_in[2];
    const float* w_v   = (const float*)d_in[3];
    const float* w_o   = (const float*)d_in[4];
    const float* qgain = (const float*)d_in[5];
    float* out = (float*)d_out;

    char* ws = (char*)d_ws;
    size_t off = 0;
    auto alloc = [&](size_t bytes) {
        char* p = ws + off;
        off += (bytes + 255) & ~(size_t)255;
        return (void*)p;
    };
    u16*   wqf  = (u16*)  alloc(3072ull * 2048 * 2);   // fused Wqkv quantized (f16 ints)
    u16*   wqo  = (u16*)  alloc(2048ull * 2048 * 2);   // Wo quantized
    float* wsc  = (float*)alloc(5120 * 4);             // w scales (fused 0..3071, Wo 3072..5119)
    float* asc  = (float*)alloc(4096 * 4);             // x token scales
    float* ysc  = (float*)alloc(4096 * 4);             // y token scales
    float* ctab = (float*)alloc(2048ull * 64 * 4);
    float* stab = (float*)alloc(2048ull * 64 * 4);
    u16*   xq   = (u16*)  alloc(4096ull * 2048 * 2);   // also reused as yq
    float* qkv  = (float*)alloc(4096ull * 3072 * 4);   // also reused as y (attn out)
    u16*   qbuf = (u16*)  alloc(2ull * 16 * 2048 * 128 * 2);
    u16*   kbuf = (u16*)  alloc(2ull * 4 * 2048 * 128 * 2);
    u16*   vbuf = (u16*)  alloc(2ull * 4 * 2048 * 128 * 2);
    u16*   vtb  = (u16*)  alloc(2ull * 4 * 128 * 2048 * 2);
    (void)ws_size; (void)in_sizes; (void)n_in; (void)out_size;

    k_rope_tables<<<512, 256, 0, stream>>>(ctab, stab);
    k_quant_rows<<<2048, 256, 0, stream>>>(w_q, wqf, wsc);
    k_quant_rows<<<512, 256, 0, stream>>>(w_k, wqf + 2048ull * 2048, wsc + 2048);
    k_quant_rows<<<512, 256, 0, stream>>>(w_v, wqf + 2560ull * 2048, wsc + 2560);
    k_quant_rows<<<2048, 256, 0, stream>>>(w_o, wqo, wsc + 3072);
    k_quant_rows<<<4096, 256, 0, stream>>>(x, xq, asc);

    k_gemm_q<<<dim3(3072 / BN, 4096 / BM), 256, 0, stream>>>(xq, wqf, asc, wsc, qkv, 4096, 3072, 2048);
    k_rmsrope<<<(4096 * 24) / 4, 256, 0, stream>>>(qkv, qgain, ctab, stab, qbuf, kbuf, vbuf);
    k_transpose_v<<<dim3(8, 32, 2), 256, 0, stream>>>(vbuf, vtb);

    float* ybuf = qkv;  // qkv dead after rmsrope; reuse as attention output
    k_attn<<<dim3(32, 16, 2), 256, 0, stream>>>(qbuf, kbuf, vtb, ybuf);

    u16* yq = xq;       // xq dead after GEMM1; reuse
    k_quant_rows<<<4096, 256, 0, stream>>>(ybuf, yq, ysc);
    k_gemm_q<<<dim3(2048 / BN, 4096 / BM), 256, 0, stream>>>(yq, wqo, ysc, wsc + 3072, out, 4096, 2048, 2048);
}

// Round 2
// 661.935 us; speedup vs baseline: 1.3762x; 1.3762x over previous
//
#include <hip/hip_runtime.h>
#include <hip/hip_fp16.h>

typedef unsigned short u16;
typedef __attribute__((ext_vector_type(8))) _Float16 f16x8;
typedef __attribute__((ext_vector_type(4))) float f32x4;

static __device__ __forceinline__ u16 f2h(float f) {
    __half h = __float2half(f);
    return __half_as_ushort(h);
}

// ---------------- RoPE tables: cos/sin[s][i], s<2048, i<64 ----------------
__global__ __launch_bounds__(256) void k_rope_tables(float* __restrict__ ct, float* __restrict__ st) {
    int idx = blockIdx.x * 256 + threadIdx.x;   // 2048*64 total
    int s = idx >> 6, i = idx & 63;
    float inv = 1.0f / powf(10000.0f, (float)i * (1.0f / 64.0f));
    float f = (float)s * inv;
    ct[idx] = cosf(f);
    st[idx] = sinf(f);
}

// ---------------- per-row absmax int8 quant (stored as exact-int f16) ----------------
__global__ __launch_bounds__(256) void k_quant_rows(const float* __restrict__ src,
        u16* __restrict__ dst, float* __restrict__ scales) {
    int row = blockIdx.x;
    const float* p = src + (size_t)row * 2048;
    int t = threadIdx.x;
    float4 v0 = ((const float4*)p)[t * 2 + 0];
    float4 v1 = ((const float4*)p)[t * 2 + 1];
    float amax = fmaxf(
        fmaxf(fmaxf(fabsf(v0.x), fabsf(v0.y)), fmaxf(fabsf(v0.z), fabsf(v0.w))),
        fmaxf(fmaxf(fabsf(v1.x), fabsf(v1.y)), fmaxf(fabsf(v1.z), fabsf(v1.w))));
#pragma unroll
    for (int d = 1; d < 64; d <<= 1) amax = fmaxf(amax, __shfl_xor(amax, d, 64));
    __shared__ float red[4];
    if ((t & 63) == 0) red[t >> 6] = amax;
    __syncthreads();
    amax = fmaxf(fmaxf(red[0], red[1]), fmaxf(red[2], red[3]));
    float scl = fmaxf(amax * (1.0f / 127.0f), 1e-5f);
    if (t == 0) scales[row] = scl;
    float vv[8] = {v0.x, v0.y, v0.z, v0.w, v1.x, v1.y, v1.z, v1.w};
    u16 q[8];
#pragma unroll
    for (int j = 0; j < 8; ++j) {
        float r = rintf(vv[j] / scl);           // RNE, matches jnp.round
        r = fminf(fmaxf(r, -127.0f), 127.0f);
        q[j] = f2h(r);                          // exact: |int| <= 127
    }
    *(uint4*)&dst[(size_t)row * 2048 + t * 8] = *(uint4*)q;
}

// ---------------- quantized GEMM: out[m][n] = (A[m,:].B[n,:]) * as[m]*ws[n] ----------------
#define BM 128
#define BN 128
#define BK 64
#define LDSP 72

__global__ __launch_bounds__(256) void k_gemm_q(const u16* __restrict__ A,
        const u16* __restrict__ B, const float* __restrict__ ascale,
        const float* __restrict__ wscale, float* __restrict__ out,
        int M, int N, int K) {
    __shared__ u16 As[BM][LDSP];
    __shared__ u16 Bs[BN][LDSP];
    int t = threadIdx.x;
    int wid = t >> 6, lane = t & 63;
    int bm = blockIdx.y * BM, bn = blockIdx.x * BN;
    int wm = (wid >> 1) * 64, wn = (wid & 1) * 64;
    int rl = lane & 15, kg = lane >> 4;

    f32x4 z = {0.f, 0.f, 0.f, 0.f};
    f32x4 acc[4][4];
#pragma unroll
    for (int i = 0; i < 4; ++i)
#pragma unroll
        for (int j = 0; j < 4; ++j) acc[i][j] = z;

    int sr = t >> 3, sc = (t & 7) * 8;
    const u16* Ab = A + (size_t)(bm + sr) * K + sc;
    const u16* Bb = B + (size_t)(bn + sr) * K + sc;
    uint4 ra[4], rb[4];
#pragma unroll
    for (int p = 0; p < 4; ++p) {
        ra[p] = *(const uint4*)(Ab + (size_t)p * 32 * K);
        rb[p] = *(const uint4*)(Bb + (size_t)p * 32 * K);
    }
    int NT = K / BK;
    for (int kt = 0; kt < NT; ++kt) {
#pragma unroll
        for (int p = 0; p < 4; ++p) {
            *(uint4*)&As[sr + p * 32][sc] = ra[p];
            *(uint4*)&Bs[sr + p * 32][sc] = rb[p];
        }
        __syncthreads();
        if (kt + 1 < NT) {
            size_t koff = (size_t)(kt + 1) * BK;
#pragma unroll
            for (int p = 0; p < 4; ++p) {
                ra[p] = *(const uint4*)(Ab + (size_t)p * 32 * K + koff);
                rb[p] = *(const uint4*)(Bb + (size_t)p * 32 * K + koff);
            }
        }
#pragma unroll
        for (int ks = 0; ks < 2; ++ks) {
            f16x8 af[4], bfr[4];
#pragma unroll
            for (int i = 0; i < 4; ++i)
                af[i] = *(const f16x8*)&As[wm + i * 16 + rl][ks * 32 + kg * 8];
#pragma unroll
            for (int j = 0; j < 4; ++j)
                bfr[j] = *(const f16x8*)&Bs[wn + j * 16 + rl][ks * 32 + kg * 8];
#pragma unroll
            for (int i = 0; i < 4; ++i)
#pragma unroll
                for (int j = 0; j < 4; ++j)
                    acc[i][j] = __builtin_amdgcn_mfma_f32_16x16x32_f16(af[i], bfr[j], acc[i][j], 0, 0, 0);
        }
        __syncthreads();
    }
#pragma unroll
    for (int i = 0; i < 4; ++i) {
#pragma unroll
        for (int j = 0; j < 4; ++j) {
            int n = bn + wn + j * 16 + rl;
            float wsn = wscale[n];
#pragma unroll
            for (int r = 0; r < 4; ++r) {
                int m = bm + wm + i * 16 + kg * 4 + r;
                out[(size_t)m * N + n] = acc[i][j][r] * ascale[m] * wsn;
            }
        }
    }
}

// ---------------- fused RMSNorm + RoPE + gain, split to q/k/v f16 buffers ----------------
__global__ __launch_bounds__(256) void k_rmsrope(const float* __restrict__ qkv,
        const float* __restrict__ qgain, const float* __restrict__ ct,
        const float* __restrict__ st, u16* __restrict__ qb,
        u16* __restrict__ kb, u16* __restrict__ vb) {
    int wave = blockIdx.x * 4 + (threadIdx.x >> 6);
    int lane = threadIdx.x & 63;
    int token = wave / 24, unit = wave - token * 24;
    int b = token >> 11, s = token & 2047;
    int col;
    if (unit < 16) col = unit * 128;
    else if (unit < 20) col = 2048 + (unit - 16) * 128;
    else col = 2560 + (unit - 20) * 128;
    const float* p = qkv + (size_t)token * 3072 + col;
    float x1 = p[lane], x2 = p[lane + 64];
    if (unit < 20) {
        float ss = x1 * x1 + x2 * x2;
#pragma unroll
        for (int d = 1; d < 64; d <<= 1) ss += __shfl_xor(ss, d, 64);
        float rn = rsqrtf(ss * (1.0f / 128.0f) + 1.1920929e-07f);
        x1 *= rn; x2 *= rn;
        float c = ct[s * 64 + lane], sn = st[s * 64 + lane];
        float o1 = x1 * c + x2 * sn;
        float o2 = x2 * c - x1 * sn;
        if (unit < 16) {
            float g = qgain[unit] * 0.08838834764831845f;  // fold 1/sqrt(128) into q
            o1 *= g; o2 *= g;
        }
        x1 = o1; x2 = o2;
    }
    u16 u1 = f2h(x1), u2 = f2h(x2);
    size_t off; u16* dst;
    if (unit < 16)      { dst = qb; off = ((size_t)(b * 16 + unit) * 2048 + s) * 128; }
    else if (unit < 20) { dst = kb; off = ((size_t)(b * 4 + (unit - 16)) * 2048 + s) * 128; }
    else                { dst = vb; off = ((size_t)(b * 4 + (unit - 20)) * 2048 + s) * 128; }
    dst[off + lane] = u1;
    dst[off + lane + 64] = u2;
}

// ---------------- V transpose: [bh][s][128] -> [bh][d][2048] ----------------
__global__ __launch_bounds__(256) void k_transpose_v(const u16* __restrict__ vb,
        u16* __restrict__ vt) {
    __shared__ u16 tls[64][72];
    int bh = blockIdx.x;
    int s0 = blockIdx.y * 64;
    int d0 = blockIdx.z * 64;
    const u16* src = vb + (size_t)bh * 2048 * 128;
    u16* dst = vt + (size_t)bh * 128 * 2048;
    int r = threadIdx.x >> 3, c = (threadIdx.x & 7) * 8;
#pragma unroll
    for (int p = 0; p < 2; ++p) {
        uint4 d4 = *(const uint4*)&src[(size_t)(s0 + r + p * 32) * 128 + d0 + c];
        u16 tmp[8]; *(uint4*)tmp = d4;
#pragma unroll
        for (int j = 0; j < 8; ++j) tls[c + j][r + p * 32] = tmp[j];
    }
    __syncthreads();
#pragma unroll
    for (int p = 0; p < 2; ++p) {
        int dd = r + p * 32;
        u16 tmp[8];
#pragma unroll
        for (int j = 0; j < 8; ++j) tmp[j] = tls[dd][c + j];
        *(uint4*)&dst[(size_t)(d0 + dd) * 2048 + s0 + c] = *(uint4*)tmp;
    }
}

// ---------------- flash attention: causal GQA, triangle-paired, pipelined ----------------
// Grid: (16 pairs, 16 heads, 2 batch). Each wave runs q-chunk `pair` then `31-pair`
// (16 q rows each) => constant ~66 kv-steps per wave: perfectly balanced grid.
__global__ __launch_bounds__(256) void k_attn(const u16* __restrict__ qb,
        const u16* __restrict__ kb, const u16* __restrict__ vt,
        float* __restrict__ y) {
    int pair = blockIdx.x, h = blockIdx.y, b = blockIdx.z;
    int wid = threadIdx.x >> 6, lane = threadIdx.x & 63;
    int kvh = h >> 2;
    int rl = lane & 15, kg = lane >> 4;
    const u16* kp = kb + (size_t)(b * 4 + kvh) * 2048 * 128;
    const u16* vp = vt + (size_t)(b * 4 + kvh) * 128 * 2048;
    __shared__ u16 Ps[4][16][40];
    f32x4 z = {0.f, 0.f, 0.f, 0.f};

    for (int phase = 0; phase < 2; ++phase) {
        int qc = (phase == 0) ? pair : (31 - pair);
        int q0 = qc * 64 + wid * 16;
        const u16* qp = qb + ((size_t)(b * 16 + h) * 2048 + q0) * 128;

        f16x8 qf[4];
#pragma unroll
        for (int kc = 0; kc < 4; ++kc)
            qf[kc] = *(const f16x8*)&qp[(size_t)rl * 128 + kc * 32 + kg * 8];

        f32x4 o[8];
#pragma unroll
        for (int j = 0; j < 8; ++j) o[j] = z;
        float mrow[4], lrow[4];
#pragma unroll
        for (int r = 0; r < 4; ++r) { mrow[r] = -3.0e38f; lrow[r] = 0.f; }

        int nsteps = (q0 + 47) >> 5;   // kv tiles of 32 covering cols <= q0+15

        // one pipelined step: uses kcur (K regs for step t), prefetches K for t+1 into knxt
        auto STEP = [&](int tstep, f16x8 (&kcur)[2][4], f16x8 (&knxt)[2][4]) {
            int kv0 = tstep * 32;
            // issue V loads early: latency hides under QK + softmax
            f16x8 vf[8];
#pragma unroll
            for (int j = 0; j < 8; ++j)
                vf[j] = *(const f16x8*)&vp[(size_t)(j * 16 + rl) * 2048 + kv0 + kg * 8];
            // QK^T
            f32x4 sc[2];
#pragma unroll
            for (int nt = 0; nt < 2; ++nt) {
                f32x4 acc = z;
#pragma unroll
                for (int kc = 0; kc < 4; ++kc)
                    acc = __builtin_amdgcn_mfma_f32_16x16x32_f16(qf[kc], kcur[nt][kc], acc, 0, 0, 0);
                sc[nt] = acc;
            }
            // prefetch next step's K: latency hides under softmax + PV
            if (tstep + 1 < nsteps) {
                int kn0 = kv0 + 32;
#pragma unroll
                for (int nt = 0; nt < 2; ++nt)
#pragma unroll
                    for (int kc = 0; kc < 4; ++kc)
                        knxt[nt][kc] = *(const f16x8*)&kp[(size_t)(kn0 + nt * 16 + rl) * 128 + kc * 32 + kg * 8];
            }
            // online softmax
            float alpha[4];
#pragma unroll
            for (int r = 0; r < 4; ++r) {
                int grow = q0 + kg * 4 + r;
                float s0v = sc[0][r], s1v = sc[1][r];
                if (kv0 + rl > grow) s0v = -3.0e38f;
                if (kv0 + 16 + rl > grow) s1v = -3.0e38f;
                float mx = fmaxf(s0v, s1v);
                mx = fmaxf(mx, __shfl_xor(mx, 1, 64));
                mx = fmaxf(mx, __shfl_xor(mx, 2, 64));
                mx = fmaxf(mx, __shfl_xor(mx, 4, 64));
                mx = fmaxf(mx, __shfl_xor(mx, 8, 64));
                float mnew = fmaxf(mrow[r], mx);
                float a = __expf(mrow[r] - mnew);
                s0v = __expf(s0v - mnew);
                s1v = __expf(s1v - mnew);
                sc[0][r] = s0v; sc[1][r] = s1v;
                float rs = s0v + s1v;
                rs += __shfl_xor(rs, 1, 64);
                rs += __shfl_xor(rs, 2, 64);
                rs += __shfl_xor(rs, 4, 64);
                rs += __shfl_xor(rs, 8, 64);
                lrow[r] = lrow[r] * a + rs;
                mrow[r] = mnew;
                alpha[r] = a;
            }
#pragma unroll
            for (int j = 0; j < 8; ++j) {
                o[j][0] *= alpha[0];
                o[j][1] *= alpha[1];
                o[j][2] *= alpha[2];
                o[j][3] *= alpha[3];
            }
            // P: C-layout -> A-layout via per-wave LDS bounce
#pragma unroll
            for (int nt = 0; nt < 2; ++nt)
#pragma unroll
                for (int r = 0; r < 4; ++r)
                    Ps[wid][kg * 4 + r][nt * 16 + rl] = f2h(sc[nt][r]);
            f16x8 pa = *(const f16x8*)&Ps[wid][rl][kg * 8];
#pragma unroll
            for (int j = 0; j < 8; ++j)
                o[j] = __builtin_amdgcn_mfma_f32_16x16x32_f16(pa, vf[j], o[j], 0, 0, 0);
        };

        f16x8 kfA[2][4], kfB[2][4];
#pragma unroll
        for (int nt = 0; nt < 2; ++nt)
#pragma unroll
            for (int kc = 0; kc < 4; ++kc)
                kfA[nt][kc] = *(const f16x8*)&kp[(size_t)(nt * 16 + rl) * 128 + kc * 32 + kg * 8];

        for (int tstep = 0; tstep < nsteps; tstep += 2) {
            STEP(tstep, kfA, kfB);
            if (tstep + 1 < nsteps) STEP(tstep + 1, kfB, kfA);
        }

#pragma unroll
        for (int r = 0; r < 4; ++r) lrow[r] = 1.0f / lrow[r];
#pragma unroll
        for (int j = 0; j < 8; ++j)
#pragma unroll
            for (int r = 0; r < 4; ++r) {
                int grow = q0 + kg * 4 + r;
                y[(size_t)(b * 2048 + grow) * 2048 + h * 128 + j * 16 + rl] = o[j][r] * lrow[r];
            }
    }
}

extern "C" void kernel_launch(void* const* d_in, const int* in_sizes, int n_in,
                              void* d_out, int out_size, void* d_ws, size_t ws_size,
                              hipStream_t stream) {
    const float* x     = (const float*)d_in[0];
    const float* w_q   = (const float*)d_in[1];
    const float* w_k   = (const float*)d_in[2];
    const float* w_v   = (const float*)d_in[3];
    const float* w_o   = (const float*)d_in[4];
    const float* qgain = (const float*)d_in[5];
    float* out = (float*)d_out;

    char* ws = (char*)d_ws;
    size_t off = 0;
    auto alloc = [&](size_t bytes) {
        char* p = ws + off;
        off += (bytes + 255) & ~(size_t)255;
        return (void*)p;
    };
    u16*   wqf  = (u16*)  alloc(3072ull * 2048 * 2);
    u16*   wqo  = (u16*)  alloc(2048ull * 2048 * 2);
    float* wsc  = (float*)alloc(5120 * 4);
    float* asc  = (float*)alloc(4096 * 4);
    float* ysc  = (float*)alloc(4096 * 4);
    float* ctab = (float*)alloc(2048ull * 64 * 4);
    float* stab = (float*)alloc(2048ull * 64 * 4);
    u16*   xq   = (u16*)  alloc(4096ull * 2048 * 2);
    float* qkv  = (float*)alloc(4096ull * 3072 * 4);
    u16*   qbuf = (u16*)  alloc(2ull * 16 * 2048 * 128 * 2);
    u16*   kbuf = (u16*)  alloc(2ull * 4 * 2048 * 128 * 2);
    u16*   vbuf = (u16*)  alloc(2ull * 4 * 2048 * 128 * 2);
    u16*   vtb  = (u16*)  alloc(2ull * 4 * 128 * 2048 * 2);
    (void)ws_size; (void)in_sizes; (void)n_in; (void)out_size;

    k_rope_tables<<<512, 256, 0, stream>>>(ctab, stab);
    k_quant_rows<<<2048, 256, 0, stream>>>(w_q, wqf, wsc);
    k_quant_rows<<<512, 256, 0, stream>>>(w_k, wqf + 2048ull * 2048, wsc + 2048);
    k_quant_rows<<<512, 256, 0, stream>>>(w_v, wqf + 2560ull * 2048, wsc + 2560);
    k_quant_rows<<<2048, 256, 0, stream>>>(w_o, wqo, wsc + 3072);
    k_quant_rows<<<4096, 256, 0, stream>>>(x, xq, asc);

    k_gemm_q<<<dim3(3072 / BN, 4096 / BM), 256, 0, stream>>>(xq, wqf, asc, wsc, qkv, 4096, 3072, 2048);
    k_rmsrope<<<(4096 * 24) / 4, 256, 0, stream>>>(qkv, qgain, ctab, stab, qbuf, kbuf, vbuf);
    k_transpose_v<<<dim3(8, 32, 2), 256, 0, stream>>>(vbuf, vtb);

    float* ybuf = qkv;
    k_attn<<<dim3(16, 16, 2), 256, 0, stream>>>(qbuf, kbuf, vtb, ybuf);

    u16* yq = xq;
    k_quant_rows<<<4096, 256, 0, stream>>>(ybuf, yq, ysc);
    k_gemm_q<<<dim3(2048 / BN, 4096 / BM), 256, 0, stream>>>(yq, wqo, ysc, wsc + 3072, out, 4096, 2048, 2048);
}